// Round 2
// baseline (531.786 us; speedup 1.0000x reference)
//
#include <hip/hip_runtime.h>
#include <math.h>

// ---- problem constants ----
#define TB        256           // threads per block = 4 waves
#define POSB      256           // positions per block = 1 per THREAD (R8: position-split)
#define NPOS      131072        // B*H*W positions
#define KCODES    512
#define DIM       64
#define HW        4096          // H*W
#define LOSS_OFF  8388608ull
#define ENC_OFF   8388609ull
#define PERP_OFF  75497473ull
#define TILE_DW   (POSB * KCODES)       // 131072 dwords: block's encodings tile
#define NF4       ((TILE_DW - 4) / 4)   // 32767 float4 after the +3 align shift
#define ROWS_PP   240                   // codebook rows per LDS pass (240,240,32)

__device__ __forceinline__ float tree8(float r0, float r1, float r2, float r3,
                                       float r4, float r5, float r6, float r7) {
    // numpy pairwise combine: ((r0+r1)+(r2+r3)) + ((r4+r5)+(r6+r7))
    return __fadd_rn(__fadd_rn(__fadd_rn(r0, r1), __fadd_rn(r2, r3)),
                     __fadd_rn(__fadd_rn(r4, r5), __fadd_rn(r6, r7)));
}

// Prep: ww[k] = sum(w[k]^2) in numpy pairwise order; zero counts + loss accumulator.
extern "C" __global__ __launch_bounds__(512)
void vq_prep(const float* __restrict__ w, float* __restrict__ ww,
             int* __restrict__ counts, float* __restrict__ lossAcc)
{
    const int k = threadIdx.x;                 // 512 threads
    const float* wk = w + k * DIM;
    float r[8];
    #pragma unroll
    for (int i = 0; i < 8; ++i) {
        #pragma unroll
        for (int j = 0; j < 8; ++j) {
            float v = wk[i * 8 + j];
            float pp = __fmul_rn(v, v);
            r[j] = (i == 0) ? pp : __fadd_rn(r[j], pp);
        }
    }
    ww[k] = tree8(r[0], r[1], r[2], r[3], r[4], r[5], r[6], r[7]);
    counts[k] = 0;
    if (k == 0) *lossAcc = 0.0f;
}

// R8: pure-DS inner loop, position-split.
// R6/R7 flaw: w rows via s_load. SMEM returns OUT OF ORDER -> compiler can only
// guard with lgkmcnt(0) full drains -> no cross-iteration prefetch; ~250+cy of
// scalar latency exposed per row regardless of occupancy (R6 4-waves/EU ~= R7
// 2-waves/EU, both ~30% VALUBusy). R1-R5 flaw was the dual: s_load(w) mixed
// with ds_read(x) on one lgkm counter. Never tried: PURE DS. Here w is staged
// to LDS (3 passes of 240/240/32 rows, exactly 64KB static -> 2 blocks/CU) and
// the loop reads it via uniform-address ds_read_b128 (broadcast = conflict-free,
// in-order, fine-grained lgkmcnt(N) -> compiler pipelines across iterations).
// Position-split (1 pos/thread, all 512 codes/thread) kills the K-merge and
// runs the epilogue on all 256 threads. FP chains bit-identical to R7.
extern "C" __global__ __launch_bounds__(TB)
__attribute__((amdgpu_waves_per_eu(2, 2)))
void vq_main(const float* __restrict__ x, const float* __restrict__ w,
             const float* __restrict__ ww, float* __restrict__ out,
             int* __restrict__ counts, float* __restrict__ lossAcc)
{
    __shared__ __align__(16) float wlds[ROWS_PP * DIM];  // 61440 B
    __shared__ float wwlds[KCODES];                      //  2048 B
    __shared__ int   hcount[KCODES];                     //  2048 B -> 65536 total

    const int tid = threadIdx.x;
    const int l   = tid & 63;                  // lane (loss reduction)
    const int n   = blockIdx.x * POSB + tid;   // my position
    const int b   = n >> 12;                   // 256 | 4096: one b per block
    const int hw  = n & 4095;

    hcount[tid]      = 0;
    hcount[tid + TB] = 0;

    // ---- prologue: my position's x into VGPRs (channel stride HW), x2 = 2x,
    // A = sum(x^2) replicating numpy pairwise_sum(64): r[j] over i ascending.
    const float* xp = x + ((size_t)b * DIM) * HW + hw;
    float x2[DIM];
    float A;
    {
        float r[8];
        #pragma unroll
        for (int i = 0; i < 8; ++i) {
            #pragma unroll
            for (int j = 0; j < 8; ++j) {
                const int d = i * 8 + j;
                float v = xp[(size_t)d * HW];
                x2[d] = v + v;                  // exact doubling
                float pp = __fmul_rn(v, v);
                r[j] = (i == 0) ? pp : __fadd_rn(r[j], pp);
            }
        }
        A = tree8(r[0], r[1], r[2], r[3], r[4], r[5], r[6], r[7]);
    }

    // encodings tile zero-fill setup (T0%4==1 -> +3 shift is 16B-aligned)
    const size_t T0 = ENC_OFF + (size_t)blockIdx.x * TILE_DW;
    float4* zs4 = reinterpret_cast<float4*>(out + T0 + 3);
    const float4 zero4 = make_float4(0.0f, 0.0f, 0.0f, 0.0f);
    if (tid < 3)  out[T0 + tid] = 0.0f;              // edge dwords 0,1,2
    if (tid == 3) out[T0 + (TILE_DW - 1)] = 0.0f;    // edge dword 131071

    float best  = INFINITY;
    int   bestk = 0;

    const float4* w4  = reinterpret_cast<const float4*>(w);
    float4*       wl4 = reinterpret_cast<float4*>(wlds);

    #pragma unroll 1
    for (int p = 0; p < 3; ++p) {
        const int k0 = (p == 0) ? 0 : ((p == 1) ? ROWS_PP : 2 * ROWS_PP);
        const int k1 = (p == 2) ? KCODES : (k0 + ROWS_PP);

        // ---- stage rows [k0,k1) into LDS: coalesced float4, conflict-free writes
        const int nf = (k1 - k0) * (DIM / 4);        // 3840,3840,512 float4
        for (int f = tid; f < nf; f += TB)
            wl4[f] = w4[k0 * (DIM / 4) + f];
        if (p == 0) {                                // ww staged once
            wwlds[tid]      = ww[tid];
            wwlds[tid + TB] = ww[tid + TB];
        }
        __syncthreads();

        // ---- scan [k0,k1): uniform-address ds_read (broadcast), pure lgkm loop;
        // interleave the coalesced float4 zero-fill of the encodings tile.
        #pragma unroll 1
        for (int k = k0; k < k1; ++k) {
            const float* row = wlds + (k - k0) * DIM;
            float s[8];
            #pragma unroll
            for (int i = 0; i < 8; ++i) {
                #pragma unroll
                for (int j = 0; j < 8; ++j) {
                    const int d = i * 8 + j;
                    float wv = row[d];
                    if (i == 0) s[j] = __fmul_rn(x2[d], wv);      // == fmaf(a,b,0)
                    else        s[j] = __fmaf_rn(x2[d], wv, s[j]);
                }
            }
            float dot  = tree8(s[0], s[1], s[2], s[3], s[4], s[5], s[6], s[7]);
            float t    = __fadd_rn(A, wwlds[k]);     // (||x||^2 + ||w_k||^2), ref order
            float dist = __fadd_rn(t, -dot);         // minus 2*x.w
            if (dist < best) { best = dist; bestk = k; }  // strict <: first min k

            if ((k & 3) == 0) {                      // 128 float4 per thread total
                const int m = (k >> 2) * TB + tid;   // covers [0,32768)
                if (m < NF4) zs4[m] = zero4;         // m=32767 is the tile edge
            }
        }
        __syncthreads();   // all waves done reading this LDS pass (and, after
                           // p==2, zero stores drained: vmcnt(0) at barrier)
    }

    // ---- epilogue: every thread owns one position (no merge needed)
    out[ENC_OFF + (size_t)n * KCODES + bestk] = 1.0f;   // one-hot after zeros
    atomicAdd(&hcount[bestk], 1);

    const float4* wrow = reinterpret_cast<const float4*>(w + (size_t)bestk * DIM);
    float* qo = out + ((size_t)b * DIM) * HW + hw;
    float sse = 0.0f;
    #pragma unroll
    for (int c = 0; c < 16; ++c) {
        float4 q = wrow[c];
        qo[(size_t)(4 * c + 0) * HW] = q.x;
        qo[(size_t)(4 * c + 1) * HW] = q.y;
        qo[(size_t)(4 * c + 2) * HW] = q.z;
        qo[(size_t)(4 * c + 3) * HW] = q.w;
        float e0 = q.x - 0.5f * x2[4 * c + 0]; sse = __fmaf_rn(e0, e0, sse);
        float e1 = q.y - 0.5f * x2[4 * c + 1]; sse = __fmaf_rn(e1, e1, sse);
        float e2 = q.z - 0.5f * x2[4 * c + 2]; sse = __fmaf_rn(e2, e2, sse);
        float e3 = q.w - 0.5f * x2[4 * c + 3]; sse = __fmaf_rn(e3, e3, sse);
    }
    // wave-level SSE reduction (64 lanes), one atomic per wave
    #pragma unroll
    for (int off = 32; off > 0; off >>= 1) sse += __shfl_down(sse, off);
    if (l == 0) atomicAdd(lossAcc, sse);

    __syncthreads();   // hcount atomics done

    // histogram drain
    {
        int c0 = hcount[tid];       if (c0) atomicAdd(&counts[tid], c0);
        int c1 = hcount[tid + TB];  if (c1) atomicAdd(&counts[tid + TB], c1);
    }
}

// Finalize: loss scalar + perplexity from histogram.
extern "C" __global__ __launch_bounds__(512)
void vq_finalize(const int* __restrict__ counts, const float* __restrict__ lossAcc,
                 float* __restrict__ out)
{
    __shared__ double sred[KCODES];
    const int t = threadIdx.x;                 // 512 threads
    double p = (double)counts[t] * (1.0 / (double)NPOS);
    sred[t] = -p * log(p + 1e-10);
    __syncthreads();
    for (int s = KCODES / 2; s > 0; s >>= 1) {
        if (t < s) sred[t] += sred[t + s];
        __syncthreads();
    }
    if (t == 0) {
        out[PERP_OFF] = (float)exp(sred[0]);
        out[LOSS_OFF] = 1.25f * (lossAcc[0] / 8388608.0f);
    }
}

extern "C" void kernel_launch(void* const* d_in, const int* in_sizes, int n_in,
                              void* d_out, int out_size, void* d_ws, size_t ws_size,
                              hipStream_t stream)
{
    const float* x = (const float*)d_in[0];    // [32,64,64,64] fp32
    const float* w = (const float*)d_in[1];    // [512,64] fp32
    float* out = (float*)d_out;

    float* ww      = (float*)d_ws;                         // 512 floats
    int*   counts  = (int*)((char*)d_ws + 2048);           // 512 ints
    float* lossAcc = (float*)((char*)d_ws + 4096);         // 1 float

    vq_prep<<<1, 512, 0, stream>>>(w, ww, counts, lossAcc);
    vq_main<<<NPOS / POSB, TB, 0, stream>>>(x, w, ww, out, counts, lossAcc);
    vq_finalize<<<1, 512, 0, stream>>>(counts, lossAcc, out);
}